// Round 1
// baseline (9896.403 us; speedup 1.0000x reference)
//
#include <hip/hip_runtime.h>
#include <hip/hip_bf16.h>
#include <cmath>

// ---------------------------------------------------------------------------
// Stacked 2-layer Elman RNN, restructured:
//   A0 = gather(emb,inputs) @ Wx0^T + bh0          (big GEMM, fused gather)
//   for t: h0[t] = tanh(A0[t] + h0[t-1] @ Wh0^T)   (70 small sequential steps)
//   A1 = H0 @ Wx1^T + bh1                          (big GEMM)
//   for t: h1[t] = tanh(A1[t] + h1[t-1] @ Wh1^T)   (70 small sequential steps)
//   logits = H1 @ Wy^T + by                        (big GEMM, 91.7 GFLOP)
//   h_final = {h0[T-1], h1[T-1]}
// All fp32 vector-ALU this round (correctness baseline).
// ---------------------------------------------------------------------------

#define BM 64
#define BN 64
#define BK 32

// C[m][n] = bias[n] + sum_k A[rowA(m)][k] * B[n][k]
// A row-major [*,K] (rowA = idx ? idx[m] : m), B row-major [N,K].
// M must be a multiple of BM; K a multiple of BK; N bounds-checked.
__global__ __launch_bounds__(256) void gemm_bt_kernel(
    const float* __restrict__ A, const float* __restrict__ B,
    const float* __restrict__ bias, float* __restrict__ C,
    const int* __restrict__ idx, int M, int N, int K)
{
    __shared__ float As[BK][BM + 1];
    __shared__ float Bs[BK][BN + 1];
    const int tid = threadIdx.x;
    const int m0 = blockIdx.y * BM;
    const int n0 = blockIdx.x * BN;
    const int tx = tid & 15;   // n-group (16 groups of 4)
    const int ty = tid >> 4;   // m-group (16 groups of 4)
    float acc[4][4] = {};

    const int nkt = K / BK;
    for (int kt = 0; kt < nkt; ++kt) {
        const int k0 = kt * BK;
        // A tile: 64 rows x 32 k = 512 float4, 2 per thread
        #pragma unroll
        for (int c = 0; c < 2; ++c) {
            int ci = c * 256 + tid;      // 0..511
            int r  = ci >> 3;            // 0..63
            int kq = ci & 7;             // 0..7
            int m  = m0 + r;
            const float* Arow = A + (size_t)(idx ? idx[m] : m) * K;
            float4 v = *reinterpret_cast<const float4*>(Arow + k0 + kq * 4);
            As[kq*4+0][r] = v.x; As[kq*4+1][r] = v.y;
            As[kq*4+2][r] = v.z; As[kq*4+3][r] = v.w;
        }
        // B tile
        #pragma unroll
        for (int c = 0; c < 2; ++c) {
            int ci = c * 256 + tid;
            int r  = ci >> 3;
            int kq = ci & 7;
            int n  = n0 + r;
            float4 v = make_float4(0.f, 0.f, 0.f, 0.f);
            if (n < N)
                v = *reinterpret_cast<const float4*>(B + (size_t)n * K + k0 + kq * 4);
            Bs[kq*4+0][r] = v.x; Bs[kq*4+1][r] = v.y;
            Bs[kq*4+2][r] = v.z; Bs[kq*4+3][r] = v.w;
        }
        __syncthreads();
        #pragma unroll
        for (int k = 0; k < BK; ++k) {
            float a[4], b[4];
            #pragma unroll
            for (int i = 0; i < 4; ++i) a[i] = As[k][ty*4 + i];
            #pragma unroll
            for (int j = 0; j < 4; ++j) b[j] = Bs[k][tx*4 + j];
            #pragma unroll
            for (int i = 0; i < 4; ++i)
                #pragma unroll
                for (int j = 0; j < 4; ++j)
                    acc[i][j] += a[i] * b[j];
        }
        __syncthreads();
    }

    #pragma unroll
    for (int i = 0; i < 4; ++i) {
        int m = m0 + ty*4 + i;
        #pragma unroll
        for (int j = 0; j < 4; ++j) {
            int n = n0 + tx*4 + j;
            if (n < N) C[(size_t)m * N + n] = acc[i][j] + bias[n];
        }
    }
}

// One recurrence step (one layer): BufT[b][j] = tanh(BufT[b][j] + sum_k Hprev[b][k]*Wh[j][k])
// grid = 256 blocks (4 j's each, all 64 b), 256 threads.
__global__ __launch_bounds__(256) void recur_kernel(
    const float* __restrict__ Wh,     // [1024][1024]
    const float* __restrict__ Hprev,  // [64][1024] previous-step h
    float* __restrict__ BufT)         // [64][1024] in: A-term, out: new h (in place)
{
    __shared__ float Hk[64][65];
    const int tid = threadIdx.x;
    const int j = blockIdx.x * 4 + (tid & 3);
    const int b = tid >> 2;
    const float* wr = Wh + (size_t)j * 1024;
    float acc = 0.f;

    for (int kt = 0; kt < 16; ++kt) {
        __syncthreads();
        // stage Hprev[:, kt*64 .. kt*64+63] : 64x64 floats = 1024 float4, 4/thread
        #pragma unroll
        for (int c = 0; c < 4; ++c) {
            int fi = c * 256 + tid;    // 0..1023
            int bl = fi >> 4;          // 0..63
            int kq = fi & 15;          // 0..15
            float4 v = *reinterpret_cast<const float4*>(
                Hprev + (size_t)bl * 1024 + kt * 64 + kq * 4);
            Hk[bl][kq*4+0] = v.x; Hk[bl][kq*4+1] = v.y;
            Hk[bl][kq*4+2] = v.z; Hk[bl][kq*4+3] = v.w;
        }
        __syncthreads();
        const float* w = wr + kt * 64;
        #pragma unroll
        for (int kk = 0; kk < 16; ++kk) {
            float4 wv = *reinterpret_cast<const float4*>(w + kk * 4);
            acc += Hk[b][kk*4+0] * wv.x + Hk[b][kk*4+1] * wv.y
                 + Hk[b][kk*4+2] * wv.z + Hk[b][kk*4+3] * wv.w;
        }
    }
    const size_t o = (size_t)b * 1024 + j;
    BufT[o] = tanhf(BufT[o] + acc);
}

__global__ __launch_bounds__(256) void copy_hfinal_kernel(
    const float* __restrict__ H0last, const float* __restrict__ H1last,
    float* __restrict__ out)
{
    int i = blockIdx.x * 256 + threadIdx.x;   // 0..65535
    out[i]         = H0last[i];
    out[65536 + i] = H1last[i];
}

extern "C" void kernel_launch(void* const* d_in, const int* in_sizes, int n_in,
                              void* d_out, int out_size, void* d_ws, size_t ws_size,
                              hipStream_t stream)
{
    const int*   inputs = (const int*)  d_in[0];
    const float* hidden = (const float*)d_in[1];
    const float* embW   = (const float*)d_in[2];
    const float* Wx0    = (const float*)d_in[3];
    const float* Wx1    = (const float*)d_in[4];
    const float* Wh0    = (const float*)d_in[5];
    const float* bh0    = (const float*)d_in[6];
    const float* Wh1    = (const float*)d_in[7];
    const float* bh1    = (const float*)d_in[8];
    const float* Wy     = (const float*)d_in[9];
    const float* by     = (const float*)d_in[10];
    float* out = (float*)d_out;

    const int T = 70, B = 64, V = 10000, E = 512, H = 1024;
    const int M = T * B;                       // 4480

    float* buf0 = (float*)d_ws;                // [M][H]  A0 -> H0 (in place)
    float* buf1 = buf0 + (size_t)M * H;        // [M][H]  A1 -> H1 (in place)

    dim3 blk(256);

    // A0 = gather(emb) @ Wx0^T + bh0
    gemm_bt_kernel<<<dim3(H / BN, M / BM), blk, 0, stream>>>(
        embW, Wx0, bh0, buf0, inputs, M, H, E);

    // layer-0 recurrence
    for (int t = 0; t < T; ++t) {
        const float* hp = (t == 0) ? hidden : (buf0 + (size_t)(t - 1) * B * H);
        recur_kernel<<<dim3(H / 4), blk, 0, stream>>>(Wh0, hp, buf0 + (size_t)t * B * H);
    }

    // A1 = H0 @ Wx1^T + bh1
    gemm_bt_kernel<<<dim3(H / BN, M / BM), blk, 0, stream>>>(
        buf0, Wx1, bh1, buf1, nullptr, M, H, H);

    // layer-1 recurrence
    for (int t = 0; t < T; ++t) {
        const float* hp = (t == 0) ? (hidden + (size_t)B * H)
                                   : (buf1 + (size_t)(t - 1) * B * H);
        recur_kernel<<<dim3(H / 4), blk, 0, stream>>>(Wh1, hp, buf1 + (size_t)t * B * H);
    }

    // logits = H1 @ Wy^T + by
    gemm_bt_kernel<<<dim3((V + BN - 1) / BN, M / BM), blk, 0, stream>>>(
        buf1, Wy, by, out, nullptr, M, V, H);

    // h_final tail
    copy_hfinal_kernel<<<dim3(256), blk, 0, stream>>>(
        buf0 + (size_t)(T - 1) * B * H, buf1 + (size_t)(T - 1) * B * H,
        out + (size_t)M * V);
}

// Round 2
// 4869.168 us; speedup vs baseline: 2.0325x; 2.0325x over previous
//
#include <hip/hip_runtime.h>
#include <hip/hip_bf16.h>
#include <cmath>
#include <cstdint>

// ---------------------------------------------------------------------------
// Stacked 2-layer Elman RNN via bf16 hi/lo-split MFMA (3-pass) everywhere.
//   setup: split weights + gathered embedding + initial hidden into bf16 hi/lo
//   A0 = embsplit @ Wx0^T + bh0                       (MFMA GEMM, fp32 out)
//   70x: h0[t]=tanh(A0[t]+h0[t-1]@Wh0^T)              (MFMA step, fused split)
//   A1 = H0split @ Wx1^T + bh1                        (MFMA GEMM)
//   70x: h1[t]=tanh(A1[t]+h1[t-1]@Wh1^T)              (MFMA step)
//   tail: h_final  (before logits overwrites aliased scratch)
//   logits = H1split @ Wy^T + by                      (MFMA GEMM, 275 GF-eff)
// ---------------------------------------------------------------------------

using u16 = unsigned short;
using u32 = unsigned int;
typedef __attribute__((ext_vector_type(8))) short short8;  // bf16x8 MFMA frag
typedef __attribute__((ext_vector_type(4))) float f32x4;

#define MFMA_BF16(a, b, c) __builtin_amdgcn_mfma_f32_16x16x32_bf16((a), (b), (c), 0, 0, 0)

__device__ __forceinline__ u16 bf16_rne(float x) {
    u32 u = __float_as_uint(x);
    u32 r = u + 0x7FFFu + ((u >> 16) & 1u);
    return (u16)(r >> 16);
}
__device__ __forceinline__ float bf16_f(u16 h) {
    return __uint_as_float(((u32)h) << 16);
}
__device__ __forceinline__ void split2(float x, u16& hi, u16& lo) {
    hi = bf16_rne(x);
    lo = bf16_rne(x - bf16_f(hi));
}

// ---------------- generic split: fp32 -> bf16 hi/lo (float4 per thread) -----
__global__ __launch_bounds__(256) void split_kernel(
    const float* __restrict__ src, u16* __restrict__ hi, u16* __restrict__ lo, int n4)
{
    int g = blockIdx.x * 256 + threadIdx.x;
    if (g >= n4) return;
    float4 v = *reinterpret_cast<const float4*>(src + (size_t)g * 4);
    u16 h0,h1,h2,h3,l0,l1,l2,l3;
    split2(v.x,h0,l0); split2(v.y,h1,l1); split2(v.z,h2,l2); split2(v.w,h3,l3);
    ushort4 H = {h0,h1,h2,h3}, L = {l0,l1,l2,l3};
    *reinterpret_cast<ushort4*>(hi + (size_t)g * 4) = H;
    *reinterpret_cast<ushort4*>(lo + (size_t)g * 4) = L;
}

// ---------------- fused gather(emb, idx) + split:  out [M][512] -------------
__global__ __launch_bounds__(256) void gather_split_kernel(
    const float* __restrict__ emb, const int* __restrict__ idx,
    u16* __restrict__ hi, u16* __restrict__ lo, int n4)
{
    int g = blockIdx.x * 256 + threadIdx.x;    // M*512/4 = 573440
    if (g >= n4) return;
    int m  = g >> 7;          // 128 float4 per row of 512
    int c4 = g & 127;
    const float* src = emb + (size_t)idx[m] * 512 + c4 * 4;
    float4 v = *reinterpret_cast<const float4*>(src);
    u16 h0,h1,h2,h3,l0,l1,l2,l3;
    split2(v.x,h0,l0); split2(v.y,h1,l1); split2(v.z,h2,l2); split2(v.w,h3,l3);
    ushort4 H = {h0,h1,h2,h3}, L = {l0,l1,l2,l3};
    size_t o = (size_t)m * 512 + c4 * 4;
    *reinterpret_cast<ushort4*>(hi + o) = H;
    *reinterpret_cast<ushort4*>(lo + o) = L;
}

// ---------------- bf16-split MFMA GEMM:  C = A @ B^T + bias ----------------
// A: [M][K] bf16 hi/lo, B: [N][K] bf16 hi/lo, C: [M][N] fp32.
// M % 128 == 0, K % 32 == 0, N bounds-checked (B rows clamped).
// Tile 128x128, BK=32, 256 threads = 4 waves of 64x64 quadrants.
// LDS tiles XOR-swizzled on 16B quads: slot(row,q) holds global quad q^(row&3).
__global__ __launch_bounds__(256) void gemm_mfma(
    const u16* __restrict__ Ah, const u16* __restrict__ Al,
    const u16* __restrict__ Bh, const u16* __restrict__ Bl,
    const float* __restrict__ bias, float* __restrict__ C,
    int M, int N, int K)
{
    __shared__ u16 sAh[128*32], sAl[128*32], sBh[128*32], sBl[128*32];
    const int tid  = threadIdx.x;
    const int lane = tid & 63;
    const int w    = tid >> 6;
    const int wr   = w >> 1, wc = w & 1;
    const int m0   = blockIdx.y * 128, n0 = blockIdx.x * 128;

    f32x4 acc[4][4];
    #pragma unroll
    for (int i = 0; i < 4; ++i)
        #pragma unroll
        for (int j = 0; j < 4; ++j) acc[i][j] = 0.0f;

    for (int k0 = 0; k0 < K; k0 += 32) {
        // reg-staged: 512 slots/tile (128 rows x 4 quads), 2 rounds x 256 thr
        #pragma unroll
        for (int r = 0; r < 2; ++r) {
            int s   = r * 256 + tid;
            int row = s >> 2, q = s & 3;
            int gq  = q ^ (row & 3);
            int l16 = row * 32 + q * 8;                 // u16 offset in tile
            size_t ga = (size_t)(m0 + row) * K + k0 + gq * 8;
            int brow = n0 + row; if (brow >= N) brow = N - 1;
            size_t gb = (size_t)brow * K + k0 + gq * 8;
            *reinterpret_cast<int4*>(sAh + l16) = *reinterpret_cast<const int4*>(Ah + ga);
            *reinterpret_cast<int4*>(sAl + l16) = *reinterpret_cast<const int4*>(Al + ga);
            *reinterpret_cast<int4*>(sBh + l16) = *reinterpret_cast<const int4*>(Bh + gb);
            *reinterpret_cast<int4*>(sBl + l16) = *reinterpret_cast<const int4*>(Bl + gb);
        }
        __syncthreads();

        const int q4 = lane >> 4;
        short8 afh[4], afl[4];
        #pragma unroll
        for (int i = 0; i < 4; ++i) {
            int ra  = wr * 64 + i * 16 + (lane & 15);
            int off = ra * 32 + (q4 ^ (ra & 3)) * 8;
            afh[i] = *reinterpret_cast<const short8*>(sAh + off);
            afl[i] = *reinterpret_cast<const short8*>(sAl + off);
        }
        #pragma unroll
        for (int j = 0; j < 4; ++j) {
            int rb  = wc * 64 + j * 16 + (lane & 15);
            int off = rb * 32 + (q4 ^ (rb & 3)) * 8;
            short8 bfh = *reinterpret_cast<const short8*>(sBh + off);
            short8 bfl = *reinterpret_cast<const short8*>(sBl + off);
            #pragma unroll
            for (int i = 0; i < 4; ++i) {
                acc[i][j] = MFMA_BF16(afh[i], bfh, acc[i][j]);
                acc[i][j] = MFMA_BF16(afh[i], bfl, acc[i][j]);
                acc[i][j] = MFMA_BF16(afl[i], bfh, acc[i][j]);
            }
        }
        __syncthreads();
    }

    // epilogue: C/D frag mapping col = lane&15, row = (lane>>4)*4 + r
    #pragma unroll
    for (int j = 0; j < 4; ++j) {
        int n = n0 + wc * 64 + j * 16 + (lane & 15);
        if (n < N) {
            float bv = bias[n];
            #pragma unroll
            for (int i = 0; i < 4; ++i) {
                #pragma unroll
                for (int r = 0; r < 4; ++r) {
                    int m = m0 + wr * 64 + i * 16 + (lane >> 4) * 4 + r;
                    C[(size_t)m * N + n] = acc[i][j][r] + bv;
                }
            }
        }
    }
}

// ---------------- one recurrence step (MFMA, fused tanh+split) -------------
// Abuf[b][j] <- tanh(Abuf[b][j] + sum_k Hprev[b][k]*Wh[j][k]);  also writes
// bf16 hi/lo of result.  M=64, N=1024, K=1024.  grid 16 blocks x 256 thr.
__global__ __launch_bounds__(256) void recur_step(
    const u16* __restrict__ Hph, const u16* __restrict__ Hpl,   // [64][1024]
    const u16* __restrict__ Whh, const u16* __restrict__ Whl,   // [1024][1024]
    float* __restrict__ Abuf,                                    // [64][1024] in/out
    u16* __restrict__ Outh, u16* __restrict__ Outl)              // [64][1024]
{
    __shared__ u16 sAh[64*32], sAl[64*32], sBh[64*32], sBl[64*32];
    const int tid  = threadIdx.x;
    const int lane = tid & 63;
    const int w    = tid >> 6;        // m-frag (rows w*16..w*16+15)
    const int n0   = blockIdx.x * 64;

    f32x4 acc[4];
    #pragma unroll
    for (int j = 0; j < 4; ++j) acc[j] = 0.0f;

    for (int k0 = 0; k0 < 1024; k0 += 32) {
        // 256 slots per tile (64 rows x 4 quads), one round
        int row = tid >> 2, q = tid & 3;
        int gq  = q ^ (row & 3);
        int l16 = row * 32 + q * 8;
        size_t ga = (size_t)row * 1024 + k0 + gq * 8;
        size_t gb = (size_t)(n0 + row) * 1024 + k0 + gq * 8;
        *reinterpret_cast<int4*>(sAh + l16) = *reinterpret_cast<const int4*>(Hph + ga);
        *reinterpret_cast<int4*>(sAl + l16) = *reinterpret_cast<const int4*>(Hpl + ga);
        *reinterpret_cast<int4*>(sBh + l16) = *reinterpret_cast<const int4*>(Whh + gb);
        *reinterpret_cast<int4*>(sBl + l16) = *reinterpret_cast<const int4*>(Whl + gb);
        __syncthreads();

        const int q4 = lane >> 4;
        int ra   = w * 16 + (lane & 15);
        int aoff = ra * 32 + (q4 ^ (ra & 3)) * 8;
        short8 ah = *reinterpret_cast<const short8*>(sAh + aoff);
        short8 al = *reinterpret_cast<const short8*>(sAl + aoff);
        #pragma unroll
        for (int j = 0; j < 4; ++j) {
            int rb   = j * 16 + (lane & 15);
            int boff = rb * 32 + (q4 ^ (rb & 3)) * 8;
            short8 bh = *reinterpret_cast<const short8*>(sBh + boff);
            short8 bl = *reinterpret_cast<const short8*>(sBl + boff);
            acc[j] = MFMA_BF16(ah, bh, acc[j]);
            acc[j] = MFMA_BF16(ah, bl, acc[j]);
            acc[j] = MFMA_BF16(al, bh, acc[j]);
        }
        __syncthreads();
    }

    #pragma unroll
    for (int j = 0; j < 4; ++j) {
        int n = n0 + j * 16 + (lane & 15);
        #pragma unroll
        for (int r = 0; r < 4; ++r) {
            int m = w * 16 + (lane >> 4) * 4 + r;
            size_t o = (size_t)m * 1024 + n;
            float h = tanhf(acc[j][r] + Abuf[o]);
            Abuf[o] = h;
            u16 hi, lo; split2(h, hi, lo);
            Outh[o] = hi; Outl[o] = lo;
        }
    }
}

// ---------------- h_final tail ---------------------------------------------
__global__ __launch_bounds__(256) void copy_hfinal_kernel(
    const float* __restrict__ H0last, const float* __restrict__ H1last,
    float* __restrict__ out)
{
    int i = blockIdx.x * 256 + threadIdx.x;   // 0..65535
    out[i]         = H0last[i];
    out[65536 + i] = H1last[i];
}

extern "C" void kernel_launch(void* const* d_in, const int* in_sizes, int n_in,
                              void* d_out, int out_size, void* d_ws, size_t ws_size,
                              hipStream_t stream)
{
    const int*   inputs = (const int*)  d_in[0];
    const float* hidden = (const float*)d_in[1];
    const float* embW   = (const float*)d_in[2];
    const float* Wx0    = (const float*)d_in[3];
    const float* Wx1    = (const float*)d_in[4];
    const float* Wh0    = (const float*)d_in[5];
    const float* bh0    = (const float*)d_in[6];
    const float* Wh1    = (const float*)d_in[7];
    const float* bh1    = (const float*)d_in[8];
    const float* Wy     = (const float*)d_in[9];
    const float* by     = (const float*)d_in[10];
    float* out = (float*)d_out;

    const int T = 70, B = 64, V = 10000, E = 512, H = 1024;
    const int M = T * B;                         // 4480
    const size_t MH = (size_t)M * H;             // 4,587,520
    const size_t BH = (size_t)B * H;             // 65,536

    // ---- workspace layout (bytes) ----
    char* wsb = (char*)d_ws;
    u16*   Wyh  = (u16*)(wsb);                        // 10000*1024 u16
    u16*   Wyl  = Wyh + (size_t)V * H;
    float* buf0 = (float*)(wsb + 40960000);           // [M][H] fp32
    u16*   H0h  = (u16*)(wsb + 59310080);
    u16*   H0l  = H0h + MH;
    u16*   H1h  = H0l + MH;
    u16*   H1l  = H1h + MH;
    u16*   Wx0h = H1l + MH;
    u16*   Wx0l = Wx0h + (size_t)H * E;
    u16*   Wx1h = Wx0l + (size_t)H * E;
    u16*   Wx1l = Wx1h + (size_t)H * H;
    u16*   Wh0h = Wx1l + (size_t)H * H;
    u16*   Wh0l = Wh0h + (size_t)H * H;
    u16*   Wh1h = Wh0l + (size_t)H * H;
    u16*   Wh1l = Wh1h + (size_t)H * H;
    u16*   hs0h = Wh1l + (size_t)H * H;
    u16*   hs0l = hs0h + BH;
    u16*   hs1h = hs0l + BH;
    u16*   hs1l = hs1h + BH;

    // ---- d_out aliased scratch (dead before logits GEMM writes) ----
    float* buf1 = out;                                // [M][H] fp32 (18.35 MB)
    u16*   Agh  = (u16*)((char*)d_out + 20971520);    // [M][E] bf16
    u16*   Agl  = Agh + (size_t)M * E;

    dim3 blk(256);

    // ---- phase 0: splits ----
    split_kernel<<<dim3((H*E)/1024), blk, 0, stream>>>(Wx0, Wx0h, Wx0l, (H*E)/4);
    split_kernel<<<dim3((H*H)/1024), blk, 0, stream>>>(Wx1, Wx1h, Wx1l, (H*H)/4);
    split_kernel<<<dim3((H*H)/1024), blk, 0, stream>>>(Wh0, Wh0h, Wh0l, (H*H)/4);
    split_kernel<<<dim3((H*H)/1024), blk, 0, stream>>>(Wh1, Wh1h, Wh1l, (H*H)/4);
    split_kernel<<<dim3((V*H)/1024), blk, 0, stream>>>(Wy,  Wyh,  Wyl,  (V*H)/4);
    split_kernel<<<dim3(64), blk, 0, stream>>>(hidden,            hs0h, hs0l, (int)BH/4);
    split_kernel<<<dim3(64), blk, 0, stream>>>(hidden + BH,       hs1h, hs1l, (int)BH/4);
    gather_split_kernel<<<dim3((M*E)/1024), blk, 0, stream>>>(embW, inputs, Agh, Agl, (M*E)/4);

    // ---- A0 = embsplit @ Wx0^T + bh0 ----
    gemm_mfma<<<dim3(H/128, M/128), blk, 0, stream>>>(
        Agh, Agl, Wx0h, Wx0l, bh0, buf0, M, H, E);

    // ---- layer-0 recurrence ----
    for (int t = 0; t < T; ++t) {
        const u16* hph = t ? (H0h + (size_t)(t-1) * BH) : hs0h;
        const u16* hpl = t ? (H0l + (size_t)(t-1) * BH) : hs0l;
        recur_step<<<dim3(16), blk, 0, stream>>>(
            hph, hpl, Wh0h, Wh0l, buf0 + (size_t)t * BH,
            H0h + (size_t)t * BH, H0l + (size_t)t * BH);
    }

    // ---- A1 = H0split @ Wx1^T + bh1 ----
    gemm_mfma<<<dim3(H/128, M/128), blk, 0, stream>>>(
        H0h, H0l, Wx1h, Wx1l, bh1, buf1, M, H, H);

    // ---- layer-1 recurrence ----
    for (int t = 0; t < T; ++t) {
        const u16* hph = t ? (H1h + (size_t)(t-1) * BH) : hs1h;
        const u16* hpl = t ? (H1l + (size_t)(t-1) * BH) : hs1l;
        recur_step<<<dim3(16), blk, 0, stream>>>(
            hph, hpl, Wh1h, Wh1l, buf1 + (size_t)t * BH,
            H1h + (size_t)t * BH, H1l + (size_t)t * BH);
    }

    // ---- tail (must precede logits GEMM: buf1 aliases d_out) ----
    copy_hfinal_kernel<<<dim3(256), blk, 0, stream>>>(
        buf0 + (size_t)(T-1) * BH, buf1 + (size_t)(T-1) * BH, out + (size_t)M * V);

    // ---- logits = H1split @ Wy^T + by ----
    gemm_mfma<<<dim3((V + 127)/128, M/128), blk, 0, stream>>>(
        H1h, H1l, Wyh, Wyl, by, out, M, V, H);
}

// Round 3
// 3281.579 us; speedup vs baseline: 3.0157x; 1.4838x over previous
//
#include <hip/hip_runtime.h>
#include <hip/hip_cooperative_groups.h>
#include <hip/hip_bf16.h>
#include <cmath>
#include <cstdint>

// ---------------------------------------------------------------------------
// Stacked 2-layer Elman RNN, bf16 hi/lo-split MFMA (3-pass) everywhere.
//   splits: weights + gathered embedding + initial hidden -> bf16 hi/lo
//   A0 = embsplit @ Wx0^T + bh0                         (MFMA GEMM)
//   persistent cooperative kernel (128 blocks, 71 grid syncs):
//     phase s: blocks 0-63:  h0[s]   = tanh(A0[s] + h0[s-1] @ Wh0^T)
//              blocks 64-127: h1[s-1] = tanh([h0[s-1];h1[s-2]] @ [Wx1;Wh1]^T + bh1)
//     weight slices resident in LDS (XOR-swizzled) for all 70 steps
//   h_final = hi+lo of t=69;  logits = H1split @ Wy^T + by   (MFMA GEMM)
// ---------------------------------------------------------------------------

using u16 = unsigned short;
using u32 = unsigned int;
typedef __attribute__((ext_vector_type(8))) short short8;  // bf16x8 MFMA frag
typedef __attribute__((ext_vector_type(4))) float f32x4;

#define MFMA_BF16(a, b, c) __builtin_amdgcn_mfma_f32_16x16x32_bf16((a), (b), (c), 0, 0, 0)

__device__ __forceinline__ u16 bf16_rne(float x) {
    u32 u = __float_as_uint(x);
    u32 r = u + 0x7FFFu + ((u >> 16) & 1u);
    return (u16)(r >> 16);
}
__device__ __forceinline__ float bf16_f(u16 h) {
    return __uint_as_float(((u32)h) << 16);
}
__device__ __forceinline__ void split2(float x, u16& hi, u16& lo) {
    hi = bf16_rne(x);
    lo = bf16_rne(x - bf16_f(hi));
}

// ---------------- generic split: fp32 -> bf16 hi/lo (float4 per thread) -----
__global__ __launch_bounds__(256) void split_kernel(
    const float* __restrict__ src, u16* __restrict__ hi, u16* __restrict__ lo, int n4)
{
    int g = blockIdx.x * 256 + threadIdx.x;
    if (g >= n4) return;
    float4 v = *reinterpret_cast<const float4*>(src + (size_t)g * 4);
    u16 h0,h1,h2,h3,l0,l1,l2,l3;
    split2(v.x,h0,l0); split2(v.y,h1,l1); split2(v.z,h2,l2); split2(v.w,h3,l3);
    ushort4 H = {h0,h1,h2,h3}, L = {l0,l1,l2,l3};
    *reinterpret_cast<ushort4*>(hi + (size_t)g * 4) = H;
    *reinterpret_cast<ushort4*>(lo + (size_t)g * 4) = L;
}

// ---------------- fused gather(emb, idx) + split:  out [M][512] -------------
__global__ __launch_bounds__(256) void gather_split_kernel(
    const float* __restrict__ emb, const int* __restrict__ idx,
    u16* __restrict__ hi, u16* __restrict__ lo, int n4)
{
    int g = blockIdx.x * 256 + threadIdx.x;    // M*512/4 = 573440
    if (g >= n4) return;
    int m  = g >> 7;
    int c4 = g & 127;
    const float* src = emb + (size_t)idx[m] * 512 + c4 * 4;
    float4 v = *reinterpret_cast<const float4*>(src);
    u16 h0,h1,h2,h3,l0,l1,l2,l3;
    split2(v.x,h0,l0); split2(v.y,h1,l1); split2(v.z,h2,l2); split2(v.w,h3,l3);
    ushort4 H = {h0,h1,h2,h3}, L = {l0,l1,l2,l3};
    size_t o = (size_t)m * 512 + c4 * 4;
    *reinterpret_cast<ushort4*>(hi + o) = H;
    *reinterpret_cast<ushort4*>(lo + o) = L;
}

// ---------------- bf16-split MFMA GEMM:  C = A @ B^T + bias ----------------
__global__ __launch_bounds__(256) void gemm_mfma(
    const u16* __restrict__ Ah, const u16* __restrict__ Al,
    const u16* __restrict__ Bh, const u16* __restrict__ Bl,
    const float* __restrict__ bias, float* __restrict__ C,
    int M, int N, int K)
{
    __shared__ u16 sAh[128*32], sAl[128*32], sBh[128*32], sBl[128*32];
    const int tid  = threadIdx.x;
    const int lane = tid & 63;
    const int w    = tid >> 6;
    const int wr   = w >> 1, wc = w & 1;
    const int m0   = blockIdx.y * 128, n0 = blockIdx.x * 128;

    f32x4 acc[4][4];
    #pragma unroll
    for (int i = 0; i < 4; ++i)
        #pragma unroll
        for (int j = 0; j < 4; ++j) acc[i][j] = 0.0f;

    for (int k0 = 0; k0 < K; k0 += 32) {
        #pragma unroll
        for (int r = 0; r < 2; ++r) {
            int s   = r * 256 + tid;
            int row = s >> 2, q = s & 3;
            int gq  = q ^ (row & 3);
            int l16 = row * 32 + q * 8;
            size_t ga = (size_t)(m0 + row) * K + k0 + gq * 8;
            int brow = n0 + row; if (brow >= N) brow = N - 1;
            size_t gb = (size_t)brow * K + k0 + gq * 8;
            *reinterpret_cast<int4*>(sAh + l16) = *reinterpret_cast<const int4*>(Ah + ga);
            *reinterpret_cast<int4*>(sAl + l16) = *reinterpret_cast<const int4*>(Al + ga);
            *reinterpret_cast<int4*>(sBh + l16) = *reinterpret_cast<const int4*>(Bh + gb);
            *reinterpret_cast<int4*>(sBl + l16) = *reinterpret_cast<const int4*>(Bl + gb);
        }
        __syncthreads();

        const int q4 = lane >> 4;
        short8 afh[4], afl[4];
        #pragma unroll
        for (int i = 0; i < 4; ++i) {
            int ra  = wr * 64 + i * 16 + (lane & 15);
            int off = ra * 32 + (q4 ^ (ra & 3)) * 8;
            afh[i] = *reinterpret_cast<const short8*>(sAh + off);
            afl[i] = *reinterpret_cast<const short8*>(sAl + off);
        }
        #pragma unroll
        for (int j = 0; j < 4; ++j) {
            int rb  = wc * 64 + j * 16 + (lane & 15);
            int off = rb * 32 + (q4 ^ (rb & 3)) * 8;
            short8 bfh = *reinterpret_cast<const short8*>(sBh + off);
            short8 bfl = *reinterpret_cast<const short8*>(sBl + off);
            #pragma unroll
            for (int i = 0; i < 4; ++i) {
                acc[i][j] = MFMA_BF16(afh[i], bfh, acc[i][j]);
                acc[i][j] = MFMA_BF16(afh[i], bfl, acc[i][j]);
                acc[i][j] = MFMA_BF16(afl[i], bfh, acc[i][j]);
            }
        }
        __syncthreads();
    }

    #pragma unroll
    for (int j = 0; j < 4; ++j) {
        int n = n0 + wc * 64 + j * 16 + (lane & 15);
        if (n < N) {
            float bv = bias[n];
            #pragma unroll
            for (int i = 0; i < 4; ++i) {
                #pragma unroll
                for (int r = 0; r < 4; ++r) {
                    int m = m0 + wr * 64 + i * 16 + (lane >> 4) * 4 + r;
                    C[(size_t)m * N + n] = acc[i][j][r] + bv;
                }
            }
        }
    }
}

// ---------------- persistent cooperative recurrence kernel -----------------
__global__ __launch_bounds__(256, 1) void rnn_persist(
    const float* __restrict__ A0,
    const u16* __restrict__ hs0h, const u16* __restrict__ hs0l,
    const u16* __restrict__ hs1h, const u16* __restrict__ hs1l,
    u16* __restrict__ H0h, u16* __restrict__ H0l,
    u16* __restrict__ H1h, u16* __restrict__ H1l,
    const u16* __restrict__ Wh0h, const u16* __restrict__ Wh0l,
    const u16* __restrict__ Wx1h, const u16* __restrict__ Wx1l,
    const u16* __restrict__ Wh1h, const u16* __restrict__ Wh1l,
    const float* __restrict__ bh1)
{
    __shared__ u16 sW[65536];          // 128 KiB: [hi | lo] halves
    const int tid   = threadIdx.x;
    const int lane  = tid & 63;
    const int w     = tid >> 6;
    const int layer = blockIdx.x >> 6;
    const int n0    = (int)(blockIdx.x & 63) * 16;
    const int m0    = w * 16;
    const int rb    = lane & 15;
    const int q4    = lane >> 4;
    const int arow  = m0 + rb;
    const size_t BH = 65536;

    cooperative_groups::grid_group grid = cooperative_groups::this_grid();

    if (layer == 0) {
        for (int i = 0; i < 16; ++i) {
            int s    = i * 256 + tid;
            int arr  = s >> 11;
            int r    = (s >> 7) & 15;
            int g    = s & 127;
            int slot = g ^ (r & 7);
            const u16* src = (arr ? Wh0l : Wh0h) + (size_t)(n0 + r) * 1024 + g * 8;
            *reinterpret_cast<int4*>(sW + arr * 16384 + r * 1024 + slot * 8) =
                *reinterpret_cast<const int4*>(src);
        }
    } else {
        for (int i = 0; i < 32; ++i) {
            int s    = i * 256 + tid;
            int arr  = s >> 12;
            int r    = (s >> 8) & 15;
            int g    = s & 255;
            int slot = g ^ (r & 7);
            const u16* src;
            if (g < 128) src = (arr ? Wx1l : Wx1h) + (size_t)(n0 + r) * 1024 + g * 8;
            else         src = (arr ? Wh1l : Wh1h) + (size_t)(n0 + r) * 1024 + (g - 128) * 8;
            *reinterpret_cast<int4*>(sW + arr * 32768 + r * 2048 + slot * 8) =
                *reinterpret_cast<const int4*>(src);
        }
    }
    __syncthreads();

    for (int s = 0; s <= 70; ++s) {
        if (layer == 0) {
            if (s < 70) {
                const int t = s;
                const u16* hph = t ? H0h + (size_t)(t - 1) * BH : hs0h;
                const u16* hpl = t ? H0l + (size_t)(t - 1) * BH : hs0l;
                f32x4 acc = {0.f, 0.f, 0.f, 0.f};
                #pragma unroll 8
                for (int kt = 0; kt < 32; ++kt) {
                    short8 ah = *reinterpret_cast<const short8*>(hph + (size_t)arow * 1024 + kt * 32 + q4 * 8);
                    short8 al = *reinterpret_cast<const short8*>(hpl + (size_t)arow * 1024 + kt * 32 + q4 * 8);
                    int slot = (kt * 4 + q4) ^ (rb & 7);
                    short8 bh = *reinterpret_cast<const short8*>(sW + rb * 1024 + slot * 8);
                    short8 bl = *reinterpret_cast<const short8*>(sW + 16384 + rb * 1024 + slot * 8);
                    acc = MFMA_BF16(ah, bh, acc);
                    acc = MFMA_BF16(ah, bl, acc);
                    acc = MFMA_BF16(al, bh, acc);
                }
                const int n = n0 + rb;
                #pragma unroll
                for (int r = 0; r < 4; ++r) {
                    int m = m0 + q4 * 4 + r;
                    size_t o = (size_t)t * BH + (size_t)m * 1024 + n;
                    float hv = tanhf(acc[r] + A0[o]);
                    u16 hi, lo; split2(hv, hi, lo);
                    H0h[o] = hi; H0l[o] = lo;
                }
            }
        } else {
            if (s >= 1) {
                const int t = s - 1;
                const u16* h0h  = H0h + (size_t)t * BH;
                const u16* h0l  = H0l + (size_t)t * BH;
                const u16* h1ph = t ? H1h + (size_t)(t - 1) * BH : hs1h;
                const u16* h1pl = t ? H1l + (size_t)(t - 1) * BH : hs1l;
                f32x4 acc = {0.f, 0.f, 0.f, 0.f};
                #pragma unroll 8
                for (int kt = 0; kt < 32; ++kt) {
                    short8 ah = *reinterpret_cast<const short8*>(h0h + (size_t)arow * 1024 + kt * 32 + q4 * 8);
                    short8 al = *reinterpret_cast<const short8*>(h0l + (size_t)arow * 1024 + kt * 32 + q4 * 8);
                    int slot = (kt * 4 + q4) ^ (rb & 7);
                    short8 bh = *reinterpret_cast<const short8*>(sW + rb * 2048 + slot * 8);
                    short8 bl = *reinterpret_cast<const short8*>(sW + 32768 + rb * 2048 + slot * 8);
                    acc = MFMA_BF16(ah, bh, acc);
                    acc = MFMA_BF16(ah, bl, acc);
                    acc = MFMA_BF16(al, bh, acc);
                }
                #pragma unroll 8
                for (int kt = 32; kt < 64; ++kt) {
                    int ko = (kt - 32) * 32;
                    short8 ah = *reinterpret_cast<const short8*>(h1ph + (size_t)arow * 1024 + ko + q4 * 8);
                    short8 al = *reinterpret_cast<const short8*>(h1pl + (size_t)arow * 1024 + ko + q4 * 8);
                    int slot = (kt * 4 + q4) ^ (rb & 7);
                    short8 bh = *reinterpret_cast<const short8*>(sW + rb * 2048 + slot * 8);
                    short8 bl = *reinterpret_cast<const short8*>(sW + 32768 + rb * 2048 + slot * 8);
                    acc = MFMA_BF16(ah, bh, acc);
                    acc = MFMA_BF16(ah, bl, acc);
                    acc = MFMA_BF16(al, bh, acc);
                }
                const int n = n0 + rb;
                #pragma unroll
                for (int r = 0; r < 4; ++r) {
                    int m = m0 + q4 * 4 + r;
                    size_t o = (size_t)t * BH + (size_t)m * 1024 + n;
                    float hv = tanhf(acc[r] + bh1[n]);
                    u16 hi, lo; split2(hv, hi, lo);
                    H1h[o] = hi; H1l[o] = lo;
                }
            }
        }
        __threadfence();
        grid.sync();
    }
}

// ---------------- h_final tail (hi+lo reconstruction) ----------------------
__global__ __launch_bounds__(256) void hfinal_kernel(
    const u16* __restrict__ H0h, const u16* __restrict__ H0l,
    const u16* __restrict__ H1h, const u16* __restrict__ H1l,
    float* __restrict__ outp)
{
    int i = blockIdx.x * 256 + threadIdx.x;
    outp[i]         = bf16_f(H0h[i]) + bf16_f(H0l[i]);
    outp[65536 + i] = bf16_f(H1h[i]) + bf16_f(H1l[i]);
}

extern "C" void kernel_launch(void* const* d_in, const int* in_sizes, int n_in,
                              void* d_out, int out_size, void* d_ws, size_t ws_size,
                              hipStream_t stream)
{
    const int*   inputs = (const int*)  d_in[0];
    const float* hidden = (const float*)d_in[1];
    const float* embW   = (const float*)d_in[2];
    const float* Wx0    = (const float*)d_in[3];
    const float* Wx1    = (const float*)d_in[4];
    const float* Wh0    = (const float*)d_in[5];
    const float* bh0    = (const float*)d_in[6];
    const float* Wh1    = (const float*)d_in[7];
    const float* bh1    = (const float*)d_in[8];
    const float* Wy     = (const float*)d_in[9];
    const float* by     = (const float*)d_in[10];
    float* out = (float*)d_out;

    const int T = 70, B = 64, V = 10000, E = 512, H = 1024;
    const int M = T * B;
    const size_t MH = (size_t)M * H;
    const size_t BH = (size_t)B * H;

    char* wsb = (char*)d_ws;
    u16*   Wyh  = (u16*)(wsb);
    u16*   Wyl  = Wyh + (size_t)V * H;
    float* buf0 = (float*)(wsb + 40960000);
    u16*   H0h  = (u16*)(wsb + 59310080);
    u16*   H0l  = H0h + MH;
    u16*   H1h  = H0l + MH;
    u16*   H1l  = H1h + MH;
    u16*   Wx0h = H1l + MH;
    u16*   Wx0l = Wx0h + (size_t)H * E;
    u16*   Wx1h = Wx0l + (size_t)H * E;
    u16*   Wx1l = Wx1h + (size_t)H * H;
    u16*   Wh0h = Wx1l + (size_t)H * H;
    u16*   Wh0l = Wh0h + (size_t)H * H;
    u16*   Wh1h = Wh0l + (size_t)H * H;
    u16*   Wh1l = Wh1h + (size_t)H * H;
    u16*   hs0h = Wh1l + (size_t)H * H;
    u16*   hs0l = hs0h + BH;
    u16*   hs1h = hs0l + BH;
    u16*   hs1l = hs1h + BH;

    u16*   Agh  = (u16*)((char*)d_out + 20971520);
    u16*   Agl  = Agh + (size_t)M * E;

    dim3 blk(256);

    split_kernel<<<dim3((H*E)/1024), blk, 0, stream>>>(Wx0, Wx0h, Wx0l, (H*E)/4);
    split_kernel<<<dim3((H*H)/1024), blk, 0, stream>>>(Wx1, Wx1h, Wx1l, (H*H)/4);
    split_kernel<<<dim3((H*H)/1024), blk, 0, stream>>>(Wh0, Wh0h, Wh0l, (H*H)/4);
    split_kernel<<<dim3((H*H)/1024), blk, 0, stream>>>(Wh1, Wh1h, Wh1l, (H*H)/4);
    split_kernel<<<dim3((V*H)/1024), blk, 0, stream>>>(Wy,  Wyh,  Wyl,  (V*H)/4);
    split_kernel<<<dim3(64), blk, 0, stream>>>(hidden,      hs0h, hs0l, (int)BH/4);
    split_kernel<<<dim3(64), blk, 0, stream>>>(hidden + BH, hs1h, hs1l, (int)BH/4);
    gather_split_kernel<<<dim3((M*E)/1024), blk, 0, stream>>>(embW, inputs, Agh, Agl, (M*E)/4);

    gemm_mfma<<<dim3(H/128, M/128), blk, 0, stream>>>(
        Agh, Agl, Wx0h, Wx0l, bh0, buf0, M, H, E);

    {
        const float* A0p = buf0;
        void* args[] = {
            (void*)&A0p,
            (void*)&hs0h, (void*)&hs0l, (void*)&hs1h, (void*)&hs1l,
            (void*)&H0h,  (void*)&H0l,  (void*)&H1h,  (void*)&H1l,
            (void*)&Wh0h, (void*)&Wh0l, (void*)&Wx1h, (void*)&Wx1l,
            (void*)&Wh1h, (void*)&Wh1l, (void*)&bh1
        };
        hipLaunchCooperativeKernel(reinterpret_cast<void*>(rnn_persist),
                                   dim3(128), blk, args, 0, stream);
    }

    hfinal_kernel<<<dim3(256), blk, 0, stream>>>(
        H0h + (size_t)(T-1) * BH, H0l + (size_t)(T-1) * BH,
        H1h + (size_t)(T-1) * BH, H1l + (size_t)(T-1) * BH,
        out + (size_t)M * V);

    gemm_mfma<<<dim3((V + 127)/128, M/128), blk, 0, stream>>>(
        H1h, H1l, Wyh, Wyl, by, out, M, V, H);
}